// Round 3
// baseline (342.455 us; speedup 1.0000x reference)
//
#include <hip/hip_runtime.h>

// ConditionalFeedForward (gpt-fast MoE FFN), MI355X. fp32 in/out.
//   x[T][H], idx[T][K], gate[E][I][H], up[E][H][I], down[E][I][H]
//   hbuf[p][o] = silu(x.gate_row) * (x.down_row);  out[p][h] = hbuf[p].up_row
// R7: R6 showed batching the butterfly was NOT the bottleneck (dur flat at
// 73us, VALU 23%, HBM 16%). New theory: vmcnt in-order semantics — x loads
// issued inside the pair loop force vmcnt(0) drains of the weight stream, so
// weight loads are never continuously in flight. Fix:
//  (a) stage x (p1) / hbuf (p2) in LDS per pair-group -> steady-state compute
//      has NO vmem loads (LDS uses lgkmcnt, doesn't drain vmem queue).
//  (b) each wave owns ROWS contiguous weight rows, register-double-buffered:
//      issue row r+1's loads, compute row r with counted vmcnt -> continuous
//      weight stream per wave, 8x fewer block restarts.
#define NE 8
#define HD 1024
#define IW 2816
#define NT 16
#define TK 2
#define NP (NT*TK)
#define NPC1 8          // pairs per staged group, phase 1 (s_x = 32 KB)
#define ROWS1 8         // o-rows per wave, phase 1; grid.x = IW/(4*ROWS1) = 88
#define NPC2 4          // pairs per staged group, phase 2 (s_h = 44 KB)
#define ROWS2 2         // h-rows per wave, phase 2; grid.x = HD/(4*ROWS2) = 128

#define LOADW(G, D, r) { _Pragma("unroll") \
    for (int c = 0; c < 4; ++c) { \
        float4 gv = *(const float4*)(gp + (size_t)(r) * HD + c * 256); \
        float4 dv = *(const float4*)(dp + (size_t)(r) * HD + c * 256); \
        G[4*c+0]=gv.x; G[4*c+1]=gv.y; G[4*c+2]=gv.z; G[4*c+3]=gv.w; \
        D[4*c+0]=dv.x; D[4*c+1]=dv.y; D[4*c+2]=dv.z; D[4*c+3]=dv.w; } }

#define COMPROW(G, D, r) { \
    float ag[NPC1], ad[NPC1]; \
    _Pragma("unroll") for (int j = 0; j < NPC1; ++j) { ag[j]=0.f; ad[j]=0.f; } \
    _Pragma("unroll") for (int j = 0; j < NPC1; ++j) if (j < nc) { \
        _Pragma("unroll") for (int c = 0; c < 4; ++c) { \
            float4 xv = *(const float4*)&s_x[j][c*256 + lane*4]; \
            ag[j] += xv.x*G[4*c+0] + xv.y*G[4*c+1] + xv.z*G[4*c+2] + xv.w*G[4*c+3]; \
            ad[j] += xv.x*D[4*c+0] + xv.y*D[4*c+1] + xv.z*D[4*c+2] + xv.w*D[4*c+3]; } } \
    _Pragma("unroll") for (int off = 32; off > 0; off >>= 1) { \
        _Pragma("unroll") for (int j = 0; j < NPC1; ++j) if (j < nc) { \
            ag[j] += __shfl_xor(ag[j], off, 64); \
            ad[j] += __shfl_xor(ad[j], off, 64); } } \
    if (lane == 0) { _Pragma("unroll") for (int j = 0; j < NPC1; ++j) if (j < nc) { \
        const float g = ag[j]; \
        const float s = g / (1.f + __expf(-g)); \
        hbuf[(size_t)s_list[g0 + j] * IW + (o0 + (r))] = s * ad[j]; } } }

// Phase 1: wave owns 8 contiguous o-rows; gate+down rows stream through a
// register double-buffer; x rows staged in LDS per pair-group.
__global__ __launch_bounds__(256) void moe_phase1(
    const float* __restrict__ x,      // [NT][HD]
    const int*   __restrict__ idx,    // [NT][TK]
    const float* __restrict__ gate,   // [NE][IW][HD]
    const float* __restrict__ down,   // [NE][IW][HD]
    float*       __restrict__ hbuf)   // [NP][IW]
{
    __shared__ float s_x[NPC1][HD];   // 32 KB
    __shared__ int s_list[NP];
    __shared__ int s_n;
    const int e = blockIdx.y;
    {
        const int t = threadIdx.x;
        const bool mine = (t < NP) && (idx[t] == e);
        const unsigned long long m = __ballot(mine);
        if (mine) s_list[__popcll(m & ((1ull << t) - 1ull))] = t;
        if (t == 0) s_n = (int)__popcll(m);
    }
    __syncthreads();
    const int npl = s_n;
    if (npl == 0) return;

    const int wave = threadIdx.x >> 6;
    const int lane = threadIdx.x & 63;
    const int o0 = (blockIdx.x * 4 + wave) * ROWS1;   // [0, 2816), rows o0..o0+7
    const float* gp = gate + ((size_t)e * IW + o0) * HD + lane * 4;
    const float* dp = down + ((size_t)e * IW + o0) * HD + lane * 4;

    for (int g0 = 0; g0 < npl; g0 += NPC1) {
        const int nc = (npl - g0 < NPC1) ? (npl - g0) : NPC1;
        __syncthreads();                              // s_x reuse barrier
        {
            const int t = threadIdx.x;                // 256 threads * 4 floats = 1 row
            for (int j = 0; j < nc; ++j) {
                const int tok = s_list[g0 + j] >> 1;  // TK==2
                *(float4*)&s_x[j][t * 4] = *(const float4*)(x + (size_t)tok * HD + t * 4);
            }
        }
        __syncthreads();

        float gA[16], dA[16], gB[16], dB[16];
        LOADW(gA, dA, 0);
        LOADW(gB, dB, 1);
        COMPROW(gA, dA, 0);
        LOADW(gA, dA, 2);
        COMPROW(gB, dB, 1);
        LOADW(gB, dB, 3);
        COMPROW(gA, dA, 2);
        LOADW(gA, dA, 4);
        COMPROW(gB, dB, 3);
        LOADW(gB, dB, 5);
        COMPROW(gA, dA, 4);
        LOADW(gA, dA, 6);
        COMPROW(gB, dB, 5);
        LOADW(gB, dB, 7);
        COMPROW(gA, dA, 6);
        COMPROW(gB, dB, 7);
    }
}

#define LOADU(W, r) { _Pragma("unroll") \
    for (int c = 0; c < 11; ++c) { \
        float4 uv = *(const float4*)(upp + (size_t)(r) * IW + c * 256); \
        W[4*c+0]=uv.x; W[4*c+1]=uv.y; W[4*c+2]=uv.z; W[4*c+3]=uv.w; } }

#define COMPH(W, r) { \
    float acc[NPC2]; \
    _Pragma("unroll") for (int j = 0; j < NPC2; ++j) acc[j] = 0.f; \
    _Pragma("unroll") for (int j = 0; j < NPC2; ++j) if (j < nc) { \
        _Pragma("unroll") for (int c = 0; c < 11; ++c) { \
            float4 hv = *(const float4*)&s_h[j][c*256 + lane*4]; \
            acc[j] += W[4*c+0]*hv.x + W[4*c+1]*hv.y + W[4*c+2]*hv.z + W[4*c+3]*hv.w; } } \
    _Pragma("unroll") for (int off = 32; off > 0; off >>= 1) { \
        _Pragma("unroll") for (int j = 0; j < NPC2; ++j) if (j < nc) \
            acc[j] += __shfl_xor(acc[j], off, 64); } \
    if (lane == 0) { _Pragma("unroll") for (int j = 0; j < NPC2; ++j) if (j < nc) \
        out[(size_t)s_list[g0 + j] * HD + (h0 + (r))] = acc[j]; } }

// Phase 2: wave owns 2 h-rows of up (reg double-buffer); hbuf rows staged in
// LDS per pair-group (1x cooperative read instead of 4x per-wave redundant).
__global__ __launch_bounds__(256) void moe_phase2(
    const float* __restrict__ up,     // [NE][HD][IW]
    const int*   __restrict__ idx,
    const float* __restrict__ hbuf,   // [NP][IW]
    float*       __restrict__ out)    // [NP][HD]
{
    __shared__ float s_h[NPC2][IW];   // 44 KB
    __shared__ int s_list[NP];
    __shared__ int s_n;
    const int e = blockIdx.y;
    {
        const int t = threadIdx.x;
        const bool mine = (t < NP) && (idx[t] == e);
        const unsigned long long m = __ballot(mine);
        if (mine) s_list[__popcll(m & ((1ull << t) - 1ull))] = t;
        if (t == 0) s_n = (int)__popcll(m);
    }
    __syncthreads();
    const int npl = s_n;
    if (npl == 0) return;

    const int wave = threadIdx.x >> 6;
    const int lane = threadIdx.x & 63;
    const int h0 = (blockIdx.x * 4 + wave) * ROWS2;   // [0, 1024), rows h0, h0+1
    const float* upp = up + ((size_t)e * HD + h0) * IW + lane * 4;

    for (int g0 = 0; g0 < npl; g0 += NPC2) {
        const int nc = (npl - g0 < NPC2) ? (npl - g0) : NPC2;
        __syncthreads();                              // s_h reuse barrier
        {
            const int t = threadIdx.x;
            for (int j = 0; j < nc; ++j) {
                const float* hr = hbuf + (size_t)s_list[g0 + j] * IW;
                for (int k = t; k < IW / 4; k += 256)  // 704 float4 per row
                    *(float4*)&s_h[j][k * 4] = *(const float4*)(hr + k * 4);
            }
        }
        __syncthreads();

        float wA[44], wB[44];
        LOADU(wA, 0);
        LOADU(wB, 1);
        COMPH(wA, 0);
        COMPH(wB, 1);
    }
}

extern "C" void kernel_launch(void* const* d_in, const int* in_sizes, int n_in,
                              void* d_out, int out_size, void* d_ws, size_t ws_size,
                              hipStream_t stream) {
    const float* x    = (const float*)d_in[0];
    const int*   idx  = (const int*)  d_in[1];
    const float* gate = (const float*)d_in[2];
    const float* up   = (const float*)d_in[3];
    const float* down = (const float*)d_in[4];
    float* hbuf = (float*)d_ws;              // 32*2816*4 = 360448 B scratch
    float* out  = (float*)d_out;             // [16][2][1024]

    moe_phase1<<<dim3(IW / (4 * ROWS1), NE), dim3(256), 0, stream>>>(x, idx, gate, down, hbuf);
    moe_phase2<<<dim3(HD / (4 * ROWS2), NE), dim3(256), 0, stream>>>(up, idx, hbuf, out);
}

// Round 4
// 286.074 us; speedup vs baseline: 1.1971x; 1.1971x over previous
//
#include <hip/hip_runtime.h>

// ConditionalFeedForward (gpt-fast MoE FFN), MI355X. fp32 in/out.
//   x[T][H], idx[T][K], gate[E][I][H], up[E][H][I], down[E][I][H]
//   hbuf[p][o] = silu(x.gate_row) * (x.down_row);  out[p][h] = hbuf[p].up_row
// R8 decomposition insight: dur_us == 2*(phase1+phase2).
//   phase2 R7 (LDS-staged hbuf + 2-row reg dbuf) was a WIN: 65 -> 35 us. KEEP.
//   phase1 R7 (8-row serial chain, 704 blocks) was the regression: occ 10%.
// Phase1 R8: back to R6's many-small-blocks shape, but each wave owns TWO
// interleaved rows with all 16 weight loads issued as ONE burst (2x in-flight
// bytes per wave at ~same waves/CU). x reads stay global (L1-resident).
// Theory: both phases plateau at ~2.5 TB/s because in-flight bytes/CU are
// latency-capped; raise waves/CU * burst-bytes.
#define NE 8
#define HD 1024
#define IW 2816
#define NT 16
#define TK 2
#define NP (NT*TK)
#define ROWS1 2         // o-rows per wave, phase 1; grid.x = IW/(4*ROWS1) = 352
#define NPC1 4          // pair chunk, phase 1 (keeps VGPR ~100)
#define NPC2 4          // pairs per staged group, phase 2 (s_h = 44 KB)
#define ROWS2 2         // h-rows per wave, phase 2; grid.x = HD/(4*ROWS2) = 128

// Phase 1: one wave per 2 adjacent (expert, o)-rows. Both rows' gate+down
// weights (16 KB/wave) issued as a single load burst; batched dots share each
// x float4 across 2 rows x 2 mats (16 FMA per x load); level-major butterfly.
__global__ __launch_bounds__(256) void moe_phase1(
    const float* __restrict__ x,      // [NT][HD]
    const int*   __restrict__ idx,    // [NT][TK]
    const float* __restrict__ gate,   // [NE][IW][HD]
    const float* __restrict__ down,   // [NE][IW][HD]
    float*       __restrict__ hbuf)   // [NP][IW]
{
    __shared__ int s_list[NP];
    __shared__ int s_n;
    const int e = blockIdx.y;
    {
        const int t = threadIdx.x;
        const bool mine = (t < NP) && (idx[t] == e);
        const unsigned long long m = __ballot(mine);
        if (mine) s_list[__popcll(m & ((1ull << t) - 1ull))] = t;
        if (t == 0) s_n = (int)__popcll(m);
    }
    __syncthreads();
    const int npl = s_n;
    if (npl == 0) return;

    const int wave = threadIdx.x >> 6;
    const int lane = threadIdx.x & 63;
    const int o0 = (blockIdx.x * 4 + wave) * ROWS1;   // rows o0, o0+1

    const float* gp = gate + ((size_t)e * IW + o0) * HD + lane * 4;
    const float* dp = down + ((size_t)e * IW + o0) * HD + lane * 4;
    float gw[ROWS1][16], dw[ROWS1][16];
    #pragma unroll
    for (int r = 0; r < ROWS1; ++r) {
        #pragma unroll
        for (int c = 0; c < 4; ++c) {                  // 16 loads, one burst
            float4 gv = *(const float4*)(gp + (size_t)r * HD + c * 256);
            float4 dv = *(const float4*)(dp + (size_t)r * HD + c * 256);
            gw[r][4*c+0]=gv.x; gw[r][4*c+1]=gv.y; gw[r][4*c+2]=gv.z; gw[r][4*c+3]=gv.w;
            dw[r][4*c+0]=dv.x; dw[r][4*c+1]=dv.y; dw[r][4*c+2]=dv.z; dw[r][4*c+3]=dv.w;
        }
    }

    for (int n0 = 0; n0 < npl; n0 += NPC1) {
        const int nc = (npl - n0 < NPC1) ? (npl - n0) : NPC1;
        float ag[ROWS1][NPC1], ad[ROWS1][NPC1];
        #pragma unroll
        for (int r = 0; r < ROWS1; ++r)
            #pragma unroll
            for (int j = 0; j < NPC1; ++j) { ag[r][j] = 0.f; ad[r][j] = 0.f; }

        #pragma unroll
        for (int j = 0; j < NPC1; ++j) {
            if (j < nc) {                              // nc wave-uniform
                const float* xrow = x + (size_t)(s_list[n0 + j] >> 1) * HD + lane * 4;
                #pragma unroll
                for (int c = 0; c < 4; ++c) {
                    float4 xv = *(const float4*)(xrow + c * 256);
                    #pragma unroll
                    for (int r = 0; r < ROWS1; ++r) {
                        ag[r][j] += xv.x*gw[r][4*c+0] + xv.y*gw[r][4*c+1]
                                  + xv.z*gw[r][4*c+2] + xv.w*gw[r][4*c+3];
                        ad[r][j] += xv.x*dw[r][4*c+0] + xv.y*dw[r][4*c+1]
                                  + xv.z*dw[r][4*c+2] + xv.w*dw[r][4*c+3];
                    }
                }
            }
        }
        // level-major butterfly: 6 dependent levels for the whole chunk
        #pragma unroll
        for (int off = 32; off > 0; off >>= 1) {
            #pragma unroll
            for (int r = 0; r < ROWS1; ++r)
                #pragma unroll
                for (int j = 0; j < NPC1; ++j)
                    if (j < nc) {
                        ag[r][j] += __shfl_xor(ag[r][j], off, 64);
                        ad[r][j] += __shfl_xor(ad[r][j], off, 64);
                    }
        }
        if (lane == 0) {
            #pragma unroll
            for (int r = 0; r < ROWS1; ++r)
                #pragma unroll
                for (int j = 0; j < NPC1; ++j)
                    if (j < nc) {
                        const float g = ag[r][j];
                        const float s = g / (1.f + __expf(-g));   // silu
                        hbuf[(size_t)s_list[n0 + j] * IW + (o0 + r)] = s * ad[r][j];
                    }
        }
    }
}

#define LOADU(W, r) { _Pragma("unroll") \
    for (int c = 0; c < 11; ++c) { \
        float4 uv = *(const float4*)(upp + (size_t)(r) * IW + c * 256); \
        W[4*c+0]=uv.x; W[4*c+1]=uv.y; W[4*c+2]=uv.z; W[4*c+3]=uv.w; } }

#define COMPH(W, r) { \
    float acc[NPC2]; \
    _Pragma("unroll") for (int j = 0; j < NPC2; ++j) acc[j] = 0.f; \
    _Pragma("unroll") for (int j = 0; j < NPC2; ++j) if (j < nc) { \
        _Pragma("unroll") for (int c = 0; c < 11; ++c) { \
            float4 hv = *(const float4*)&s_h[j][c*256 + lane*4]; \
            acc[j] += W[4*c+0]*hv.x + W[4*c+1]*hv.y + W[4*c+2]*hv.z + W[4*c+3]*hv.w; } } \
    _Pragma("unroll") for (int off = 32; off > 0; off >>= 1) { \
        _Pragma("unroll") for (int j = 0; j < NPC2; ++j) if (j < nc) \
            acc[j] += __shfl_xor(acc[j], off, 64); } \
    if (lane == 0) { _Pragma("unroll") for (int j = 0; j < NPC2; ++j) if (j < nc) \
        out[(size_t)s_list[g0 + j] * HD + (h0 + (r))] = acc[j]; } }

// Phase 2 (R7 winner, unchanged): wave owns 2 h-rows of up (reg dbuf); hbuf
// rows staged in LDS per pair-group (cooperative, non-redundant).
__global__ __launch_bounds__(256) void moe_phase2(
    const float* __restrict__ up,     // [NE][HD][IW]
    const int*   __restrict__ idx,
    const float* __restrict__ hbuf,   // [NP][IW]
    float*       __restrict__ out)    // [NP][HD]
{
    __shared__ float s_h[NPC2][IW];   // 44 KB
    __shared__ int s_list[NP];
    __shared__ int s_n;
    const int e = blockIdx.y;
    {
        const int t = threadIdx.x;
        const bool mine = (t < NP) && (idx[t] == e);
        const unsigned long long m = __ballot(mine);
        if (mine) s_list[__popcll(m & ((1ull << t) - 1ull))] = t;
        if (t == 0) s_n = (int)__popcll(m);
    }
    __syncthreads();
    const int npl = s_n;
    if (npl == 0) return;

    const int wave = threadIdx.x >> 6;
    const int lane = threadIdx.x & 63;
    const int h0 = (blockIdx.x * 4 + wave) * ROWS2;   // rows h0, h0+1
    const float* upp = up + ((size_t)e * HD + h0) * IW + lane * 4;

    for (int g0 = 0; g0 < npl; g0 += NPC2) {
        const int nc = (npl - g0 < NPC2) ? (npl - g0) : NPC2;
        __syncthreads();                              // s_h reuse barrier
        {
            const int t = threadIdx.x;
            for (int j = 0; j < nc; ++j) {
                const float* hr = hbuf + (size_t)s_list[g0 + j] * IW;
                for (int k = t; k < IW / 4; k += 256)  // 704 float4 per row
                    *(float4*)&s_h[j][k * 4] = *(const float4*)(hr + k * 4);
            }
        }
        __syncthreads();

        float wA[44], wB[44];
        LOADU(wA, 0);
        LOADU(wB, 1);
        COMPH(wA, 0);
        COMPH(wB, 1);
    }
}

extern "C" void kernel_launch(void* const* d_in, const int* in_sizes, int n_in,
                              void* d_out, int out_size, void* d_ws, size_t ws_size,
                              hipStream_t stream) {
    const float* x    = (const float*)d_in[0];
    const int*   idx  = (const int*)  d_in[1];
    const float* gate = (const float*)d_in[2];
    const float* up   = (const float*)d_in[3];
    const float* down = (const float*)d_in[4];
    float* hbuf = (float*)d_ws;              // 32*2816*4 = 360448 B scratch
    float* out  = (float*)d_out;             // [16][2][1024]

    moe_phase1<<<dim3(IW / (4 * ROWS1), NE), dim3(256), 0, stream>>>(x, idx, gate, down, hbuf);
    moe_phase2<<<dim3(HD / (4 * ROWS2), NE), dim3(256), 0, stream>>>(up, idx, hbuf, out);
}

// Round 5
// 275.855 us; speedup vs baseline: 1.2414x; 1.0370x over previous
//
#include <hip/hip_runtime.h>

// ConditionalFeedForward (gpt-fast MoE FFN), MI355X. fp32 in/out.
//   x[T][H], idx[T][K], gate[E][I][H], up[E][H][I], down[E][I][H]
//   hbuf[p][o] = silu(x.gate_row) * (x.down_row);  out[p][h] = hbuf[p].up_row
// R9 model: dur = phase1 + ~205us(phase2+fixed overhead); phase1 pinned at
// 73-75us (2.45 TB/s eff) across occupancy 10-72%, burst 8-16KB, VGPR 32-152,
// with FETCH_SIZE invariant at 90.5 MB. Theory: L3 THRASH — working set
// 276 MB (gate 92 + down 92 + up 92) > 256 MB L3; LRU streams thrash, HBM
// serves scattered evictions at 1.25 TB/s. Fix: explicit cache partition —
//  (a) `up` loaded NON-TEMPORAL (no L3 allocate) -> gate+down (184 MB) stay
//      L3-resident; phase1 ~all-L3; phase2 = clean linear HBM stream.
//  (b) XCD-aware contiguous-chunk block swizzle (T1) in both phases so each
//      XCD's miss stream is linear.
#define NE 8
#define HD 1024
#define IW 2816
#define NT 16
#define TK 2
#define NP (NT*TK)
#define ROWS1 2         // o-rows per wave, phase 1; grid.x = IW/(4*ROWS1) = 352
#define NPC1 4          // pair chunk, phase 1 (VGPR ~60)
#define NPC2 4          // pairs per staged group, phase 2 (s_h = 44 KB)
#define ROWS2 2         // h-rows per wave, phase 2; grid.x = HD/(4*ROWS2) = 128

typedef float vf4 __attribute__((ext_vector_type(4)));
__device__ __forceinline__ vf4 nt_load4(const float* p) {
    return __builtin_nontemporal_load((const vf4*)p);
}

// Phase 1: one wave per 2 adjacent (expert, o)-rows; 16-load burst of
// gate+down rows (NORMAL loads -> L3-cacheable); batched dots; level-major
// butterfly. bx swizzled so each XCD owns a contiguous 352-row slice.
__global__ __launch_bounds__(256) void moe_phase1(
    const float* __restrict__ x,      // [NT][HD]
    const int*   __restrict__ idx,    // [NT][TK]
    const float* __restrict__ gate,   // [NE][IW][HD]
    const float* __restrict__ down,   // [NE][IW][HD]
    float*       __restrict__ hbuf)   // [NP][IW]
{
    __shared__ int s_list[NP];
    __shared__ int s_n;
    const int e = blockIdx.y;
    {
        const int t = threadIdx.x;
        const bool mine = (t < NP) && (idx[t] == e);
        const unsigned long long m = __ballot(mine);
        if (mine) s_list[__popcll(m & ((1ull << t) - 1ull))] = t;
        if (t == 0) s_n = (int)__popcll(m);
    }
    __syncthreads();
    const int npl = s_n;
    if (npl == 0) return;

    // XCD swizzle: 352 = 8*44; xcd k gets bx [k*44, (k+1)*44) = contiguous rows
    const int bx = (blockIdx.x & 7) * 44 + (blockIdx.x >> 3);

    const int wave = threadIdx.x >> 6;
    const int lane = threadIdx.x & 63;
    const int o0 = (bx * 4 + wave) * ROWS1;   // rows o0, o0+1

    const float* gp = gate + ((size_t)e * IW + o0) * HD + lane * 4;
    const float* dp = down + ((size_t)e * IW + o0) * HD + lane * 4;
    float gw[ROWS1][16], dw[ROWS1][16];
    #pragma unroll
    for (int r = 0; r < ROWS1; ++r) {
        #pragma unroll
        for (int c = 0; c < 4; ++c) {                  // 16 loads, one burst
            float4 gv = *(const float4*)(gp + (size_t)r * HD + c * 256);
            float4 dv = *(const float4*)(dp + (size_t)r * HD + c * 256);
            gw[r][4*c+0]=gv.x; gw[r][4*c+1]=gv.y; gw[r][4*c+2]=gv.z; gw[r][4*c+3]=gv.w;
            dw[r][4*c+0]=dv.x; dw[r][4*c+1]=dv.y; dw[r][4*c+2]=dv.z; dw[r][4*c+3]=dv.w;
        }
    }

    for (int n0 = 0; n0 < npl; n0 += NPC1) {
        const int nc = (npl - n0 < NPC1) ? (npl - n0) : NPC1;
        float ag[ROWS1][NPC1], ad[ROWS1][NPC1];
        #pragma unroll
        for (int r = 0; r < ROWS1; ++r)
            #pragma unroll
            for (int j = 0; j < NPC1; ++j) { ag[r][j] = 0.f; ad[r][j] = 0.f; }

        #pragma unroll
        for (int j = 0; j < NPC1; ++j) {
            if (j < nc) {                              // nc wave-uniform
                const float* xrow = x + (size_t)(s_list[n0 + j] >> 1) * HD + lane * 4;
                #pragma unroll
                for (int c = 0; c < 4; ++c) {
                    float4 xv = *(const float4*)(xrow + c * 256);
                    #pragma unroll
                    for (int r = 0; r < ROWS1; ++r) {
                        ag[r][j] += xv.x*gw[r][4*c+0] + xv.y*gw[r][4*c+1]
                                  + xv.z*gw[r][4*c+2] + xv.w*gw[r][4*c+3];
                        ad[r][j] += xv.x*dw[r][4*c+0] + xv.y*dw[r][4*c+1]
                                  + xv.z*dw[r][4*c+2] + xv.w*dw[r][4*c+3];
                    }
                }
            }
        }
        #pragma unroll
        for (int off = 32; off > 0; off >>= 1) {
            #pragma unroll
            for (int r = 0; r < ROWS1; ++r)
                #pragma unroll
                for (int j = 0; j < NPC1; ++j)
                    if (j < nc) {
                        ag[r][j] += __shfl_xor(ag[r][j], off, 64);
                        ad[r][j] += __shfl_xor(ad[r][j], off, 64);
                    }
        }
        if (lane == 0) {
            #pragma unroll
            for (int r = 0; r < ROWS1; ++r)
                #pragma unroll
                for (int j = 0; j < NPC1; ++j)
                    if (j < nc) {
                        const float g = ag[r][j];
                        const float s = g / (1.f + __expf(-g));   // silu
                        hbuf[(size_t)s_list[n0 + j] * IW + (o0 + r)] = s * ad[r][j];
                    }
        }
    }
}

#define LOADU(W, r) { _Pragma("unroll") \
    for (int c = 0; c < 11; ++c) { \
        vf4 uv = nt_load4(upp + (size_t)(r) * IW + c * 256); \
        W[4*c+0]=uv.x; W[4*c+1]=uv.y; W[4*c+2]=uv.z; W[4*c+3]=uv.w; } }

#define COMPH(W, r) { \
    float acc[NPC2]; \
    _Pragma("unroll") for (int j = 0; j < NPC2; ++j) acc[j] = 0.f; \
    _Pragma("unroll") for (int j = 0; j < NPC2; ++j) if (j < nc) { \
        _Pragma("unroll") for (int c = 0; c < 11; ++c) { \
            float4 hv = *(const float4*)&s_h[j][c*256 + lane*4]; \
            acc[j] += W[4*c+0]*hv.x + W[4*c+1]*hv.y + W[4*c+2]*hv.z + W[4*c+3]*hv.w; } } \
    _Pragma("unroll") for (int off = 32; off > 0; off >>= 1) { \
        _Pragma("unroll") for (int j = 0; j < NPC2; ++j) if (j < nc) \
            acc[j] += __shfl_xor(acc[j], off, 64); } \
    if (lane == 0) { _Pragma("unroll") for (int j = 0; j < NPC2; ++j) if (j < nc) \
        out[(size_t)s_list[g0 + j] * HD + (h0 + (r))] = acc[j]; } }

// Phase 2: wave owns 2 h-rows of up, read NON-TEMPORAL (pure HBM stream, no
// L3 pollution); hbuf rows staged in LDS per pair-group.
__global__ __launch_bounds__(256) void moe_phase2(
    const float* __restrict__ up,     // [NE][HD][IW]
    const int*   __restrict__ idx,
    const float* __restrict__ hbuf,   // [NP][IW]
    float*       __restrict__ out)    // [NP][HD]
{
    __shared__ float s_h[NPC2][IW];   // 44 KB
    __shared__ int s_list[NP];
    __shared__ int s_n;
    const int e = blockIdx.y;
    {
        const int t = threadIdx.x;
        const bool mine = (t < NP) && (idx[t] == e);
        const unsigned long long m = __ballot(mine);
        if (mine) s_list[__popcll(m & ((1ull << t) - 1ull))] = t;
        if (t == 0) s_n = (int)__popcll(m);
    }
    __syncthreads();
    const int npl = s_n;
    if (npl == 0) return;

    // XCD swizzle: 128 = 8*16; xcd k gets bx [k*16, (k+1)*16)
    const int bx = (blockIdx.x & 7) * 16 + (blockIdx.x >> 3);

    const int wave = threadIdx.x >> 6;
    const int lane = threadIdx.x & 63;
    const int h0 = (bx * 4 + wave) * ROWS2;   // rows h0, h0+1
    const float* upp = up + ((size_t)e * HD + h0) * IW + lane * 4;

    for (int g0 = 0; g0 < npl; g0 += NPC2) {
        const int nc = (npl - g0 < NPC2) ? (npl - g0) : NPC2;
        __syncthreads();                              // s_h reuse barrier
        {
            const int t = threadIdx.x;
            for (int j = 0; j < nc; ++j) {
                const float* hr = hbuf + (size_t)s_list[g0 + j] * IW;
                for (int k = t; k < IW / 4; k += 256)  // 704 float4 per row
                    *(float4*)&s_h[j][k * 4] = *(const float4*)(hr + k * 4);
            }
        }
        __syncthreads();

        float wA[44], wB[44];
        LOADU(wA, 0);
        LOADU(wB, 1);
        COMPH(wA, 0);
        COMPH(wB, 1);
    }
}

extern "C" void kernel_launch(void* const* d_in, const int* in_sizes, int n_in,
                              void* d_out, int out_size, void* d_ws, size_t ws_size,
                              hipStream_t stream) {
    const float* x    = (const float*)d_in[0];
    const int*   idx  = (const int*)  d_in[1];
    const float* gate = (const float*)d_in[2];
    const float* up   = (const float*)d_in[3];
    const float* down = (const float*)d_in[4];
    float* hbuf = (float*)d_ws;              // 32*2816*4 = 360448 B scratch
    float* out  = (float*)d_out;             // [16][2][1024]

    moe_phase1<<<dim3(IW / (4 * ROWS1), NE), dim3(256), 0, stream>>>(x, idx, gate, down, hbuf);
    moe_phase2<<<dim3(HD / (4 * ROWS2), NE), dim3(256), 0, stream>>>(up, idx, hbuf, out);
}